// Round 15
// baseline (1066.651 us; speedup 1.0000x reference)
//
#include <hip/hip_runtime.h>
#include <hip/hip_bf16.h>
#include <math.h>

#define NNODES 100000
#define NFEAT 512
#define NHID 256
#define NCLS 64
#define ALPHA_C 0.1f
#define NBUCKET 512   // coarse row-buckets for 2-level scatter
#define NPB 512       // partition blocks (edge chunks)
#define RB2 196       // rows per bucket: ceil(100000/512)

typedef short s16x8 __attribute__((ext_vector_type(8)));
typedef float f32x4 __attribute__((ext_vector_type(4)));

__device__ inline unsigned short f2b(float f) {
    union { float f; unsigned u; } v; v.f = f;
    unsigned r = v.u + 0x7fff + ((v.u >> 16) & 1);   // RNE
    return (unsigned short)(r >> 16);
}
__device__ inline float b2f(unsigned short b) {
    return __uint_as_float((unsigned)b << 16);
}
__device__ inline float blo(unsigned u) { return __uint_as_float(u << 16); }
__device__ inline float bhi(unsigned u) { return __uint_as_float(u & 0xffff0000u); }
// HW packed fp32->bf16 (gfx950): dst.lo = bf16(a), dst.hi = bf16(b)
__device__ inline unsigned cvtpk(float a, float b) {
    unsigned r;
    asm("v_cvt_pk_bf16_f32 %0, %1, %2" : "=v"(r) : "v"(a), "v"(b));
    return r;
}

// ---------------- transpose+convert: dst[C][R] bf16 <- src[R][C] fp32 ----------------
__global__ __launch_bounds__(256) void cvtT_kernel(
    const float* __restrict__ src, unsigned short* __restrict__ dst, int R, int Clog2)
{
    int idx = blockIdx.x * 256 + threadIdx.x;
    int C = 1 << Clog2;
    if (idx < R * C) {
        int r = idx >> Clog2, c = idx & (C - 1);
        dst[(size_t)c * R + r] = f2b(src[idx]);
    }
}

// -------- fused MFMA MLP (fp32 feat, HW packed cvt): h = relu(f@W1+b1)@W2+b2 --------
#define HID_STRIDE 264   // 256 + 8 pad

__global__ __launch_bounds__(256) void mlp_mfma_kernel(
    const float* __restrict__ feat, const unsigned short* __restrict__ W1T,
    const float* __restrict__ b1, const unsigned short* __restrict__ W2T,
    const float* __restrict__ b2, unsigned short* __restrict__ h, int N)
{
    __shared__ unsigned short hid_s[64 * HID_STRIDE];
    const int tid  = threadIdx.x;
    const int w    = tid >> 6;
    const int lane = tid & 63;
    const int lr   = lane & 15;
    const int lh   = lane >> 4;
    const int m0   = blockIdx.x * 64;

    f32x4 acc[4][4];
#pragma unroll
    for (int i = 0; i < 4; ++i)
#pragma unroll
        for (int j = 0; j < 4; ++j) acc[i][j] = (f32x4)0.f;

    const float* arow[4];
#pragma unroll
    for (int mi = 0; mi < 4; ++mi) {
        int r = m0 + mi * 16 + lr;
        if (r > N - 1) r = N - 1;
        arow[mi] = feat + (size_t)r * NFEAT;
    }
    const unsigned short* brow[4];
#pragma unroll
    for (int nj = 0; nj < 4; ++nj)
        brow[nj] = W1T + (size_t)(w * 64 + nj * 16 + lr) * NFEAT;

    for (int kb = 0; kb < NFEAT; kb += 32) {
        const int k0 = kb + lh * 8;
        s16x8 afr[4], bfr[4];
#pragma unroll
        for (int mi = 0; mi < 4; ++mi) {
            float4 f0 = *reinterpret_cast<const float4*>(arow[mi] + k0);
            float4 f1 = *reinterpret_cast<const float4*>(arow[mi] + k0 + 4);
            union { s16x8 v; unsigned u[4]; } cv;
            cv.u[0] = cvtpk(f0.x, f0.y);
            cv.u[1] = cvtpk(f0.z, f0.w);
            cv.u[2] = cvtpk(f1.x, f1.y);
            cv.u[3] = cvtpk(f1.z, f1.w);
            afr[mi] = cv.v;
        }
#pragma unroll
        for (int nj = 0; nj < 4; ++nj)
            bfr[nj] = *reinterpret_cast<const s16x8*>(brow[nj] + k0);
#pragma unroll
        for (int mi = 0; mi < 4; ++mi)
#pragma unroll
            for (int nj = 0; nj < 4; ++nj)
                acc[mi][nj] = __builtin_amdgcn_mfma_f32_16x16x32_bf16(
                    afr[mi], bfr[nj], acc[mi][nj], 0, 0, 0);
    }

#pragma unroll
    for (int nj = 0; nj < 4; ++nj) {
        int col = w * 64 + nj * 16 + lr;
        float bias = b1[col];
#pragma unroll
        for (int mi = 0; mi < 4; ++mi)
#pragma unroll
            for (int q = 0; q < 4; ++q) {
                int row = mi * 16 + lh * 4 + q;
                hid_s[row * HID_STRIDE + col] = f2b(fmaxf(acc[mi][nj][q] + bias, 0.f));
            }
    }
    __syncthreads();

    f32x4 acc2[4];
#pragma unroll
    for (int i = 0; i < 4; ++i) acc2[i] = (f32x4)0.f;
    const int cw = w * 16;
    const unsigned short* b2row = W2T + (size_t)(cw + lr) * NHID;
    for (int ks = 0; ks < NHID; ks += 32) {
        int k0 = ks + lh * 8;
        s16x8 bfr = *reinterpret_cast<const s16x8*>(b2row + k0);
#pragma unroll
        for (int mi = 0; mi < 4; ++mi) {
            s16x8 afr = *reinterpret_cast<const s16x8*>(
                &hid_s[(mi * 16 + lr) * HID_STRIDE + k0]);
            acc2[mi] = __builtin_amdgcn_mfma_f32_16x16x32_bf16(afr, bfr, acc2[mi], 0, 0, 0);
        }
    }
    int col = cw + lr;
    float bias2 = b2[col];
#pragma unroll
    for (int mi = 0; mi < 4; ++mi)
#pragma unroll
        for (int q = 0; q < 4; ++q) {
            int row = m0 + mi * 16 + lh * 4 + q;
            if (row < N) h[(size_t)row * NCLS + col] = f2b(acc2[mi][q] + bias2);
        }
}

// ---------------- 3-phase scan ----------------
__global__ __launch_bounds__(1024) void scanA_kernel(
    const int* __restrict__ cnt, int* __restrict__ excl, int* __restrict__ partials, int n)
{
    __shared__ int wsum[16];
    const int t = threadIdx.x, wid = t >> 6, lane = t & 63;
    const int i = blockIdx.x * 1024 + t;
    int c = (i < n) ? cnt[i] : 0;
    int x = c;
#pragma unroll
    for (int off = 1; off < 64; off <<= 1) {
        int y = __shfl_up(x, off);
        if (lane >= off) x += y;
    }
    if (lane == 63) wsum[wid] = x;
    __syncthreads();
    if (wid == 0 && lane < 16) {
        int wv = wsum[lane];
#pragma unroll
        for (int off = 1; off < 16; off <<= 1) {
            int y = __shfl_up(wv, off);
            if (lane >= off) wv += y;
        }
        wsum[lane] = wv;
    }
    __syncthreads();
    int woff = wid ? wsum[wid - 1] : 0;
    int incl = x + woff;
    if (i < n) excl[i] = incl - c;
    if (t == 1023) partials[blockIdx.x] = incl;
}

__global__ __launch_bounds__(256) void scanB_kernel(
    int* __restrict__ partials, int* __restrict__ total_out, int nb, int n)
{
    __shared__ int s[256];
    const int t = threadIdx.x;
    int v = (t < nb) ? partials[t] : 0;
    s[t] = v;
    __syncthreads();
    for (int off = 1; off < 256; off <<= 1) {
        int y = (t >= off) ? s[t - off] : 0;
        __syncthreads();
        s[t] += y;
        __syncthreads();
    }
    partials[t] = s[t] - v;
    if (t == 255) total_out[n] = s[255];
}

__global__ __launch_bounds__(1024) void scanC_kernel(
    int* __restrict__ arr, const int* __restrict__ partials, int n)
{
    const int i = blockIdx.x * 1024 + threadIdx.x;
    if (i < n) arr[i] += partials[blockIdx.x];
}

// ------------- 2-level scatter (round-8 proven) -------------
__global__ __launch_bounds__(256) void countP1_kernel(
    const int* __restrict__ erow, int* __restrict__ cnts, int E, int CE)
{
    __shared__ int c[NBUCKET];
    const int blk = blockIdx.x, t = threadIdx.x;
    for (int i = t; i < NBUCKET; i += 256) c[i] = 0;
    __syncthreads();
    const int e0 = blk * CE, e1 = min(e0 + CE, E);
    for (int e = e0 + t; e < e1; e += 256)
        atomicAdd(&c[erow[e] / RB2], 1);
    __syncthreads();
    for (int b = t; b < NBUCKET; b += 256)
        cnts[(size_t)b * NPB + blk] = c[b];
}

__global__ __launch_bounds__(256) void scatterA_kernel(
    const float* __restrict__ vals, const int* __restrict__ erow,
    const int* __restrict__ ecol, const int* __restrict__ S,
    unsigned long long* __restrict__ stage, int E, int CE)
{
    __shared__ int lcur[NBUCKET];
    const int blk = blockIdx.x, t = threadIdx.x;
    for (int b = t; b < NBUCKET; b += 256) lcur[b] = S[(size_t)b * NPB + blk];
    __syncthreads();
    const int e0 = blk * CE, e1 = min(e0 + CE, E);
    for (int e = e0 + t; e < e1; e += 256) {
        int r = erow[e];
        unsigned q = (unsigned)__float2int_rn(vals[e] * 1048576.f);
        if (q > 32767u) q = 32767u;
        unsigned lo = ((unsigned)ecol[e] << 15) | q;
        int pos = atomicAdd(&lcur[r / RB2], 1);
        stage[pos] = ((unsigned long long)(unsigned)r << 32) | lo;
    }
}

__global__ __launch_bounds__(256) void scatterB_kernel(
    const unsigned long long* __restrict__ stage, const int* __restrict__ S,
    unsigned* __restrict__ ep, int* __restrict__ row_ptr, int n, int E)
{
    __shared__ int hcnt[256];
    __shared__ int lcur[256];
    const int b = blockIdx.x, t = threadIdx.x;
    if (b == 0 && t == 0) row_ptr[n] = E;
    const int r0 = b * RB2;
    if (r0 >= n) return;
    const int nr = min(RB2, n - r0);
    const int s0 = S[(size_t)b * NPB];
    const int s1 = S[(size_t)(b + 1) * NPB];
    hcnt[t] = 0;
    __syncthreads();
    for (int i = s0 + t; i < s1; i += 256)
        atomicAdd(&hcnt[(int)(stage[i] >> 32) - r0], 1);
    __syncthreads();
    int v = hcnt[t];
    lcur[t] = v;
    __syncthreads();
    for (int off = 1; off < 256; off <<= 1) {
        int y = (t >= off) ? lcur[t - off] : 0;
        __syncthreads();
        lcur[t] += y;
        __syncthreads();
    }
    int excl = lcur[t] - v;
    if (t < nr) row_ptr[r0 + t] = s0 + excl;
    __syncthreads();
    lcur[t] = s0 + excl;
    __syncthreads();
    for (int i = s0 + t; i < s1; i += 256) {
        unsigned long long rec = stage[i];
        int r = (int)(rec >> 32);
        int p = atomicAdd(&lcur[r - r0], 1);
        ep[p] = (unsigned)rec;
    }
}

// ------- SPMM + APPNP update (bf16 state): x_out = 0.9*A*x_in + 0.1*h -------
// wave = 4 edge-groups x 16 lanes; 32-edge superstep. LAST=1 fuses log_softmax
// (group-0 lanes hold the full 64-ch row: 4 ch/lane x 16 lanes).
template<int LAST>
__global__ __launch_bounds__(256) void spmm_kernel(
    const unsigned short* __restrict__ x_in, const unsigned short* __restrict__ h,
    unsigned short* __restrict__ x_out, float* __restrict__ out,
    const int* __restrict__ row_ptr, const unsigned* __restrict__ ep, int n)
{
    const int wid = threadIdx.x >> 6, lane = threadIdx.x & 63;
    const int r = blockIdx.x * 4 + wid;
    if (r >= n) return;
    const int g  = lane >> 4;
    const int li = lane & 15;
    const int s = row_ptr[r], e_end = row_ptr[r + 1];

    float aA0 = 0.f, aA1 = 0.f, aA2 = 0.f, aA3 = 0.f;
    float aB0 = 0.f, aB1 = 0.f, aB2 = 0.f, aB3 = 0.f;
    float aC0 = 0.f, aC1 = 0.f, aC2 = 0.f, aC3 = 0.f;
    float aD0 = 0.f, aD1 = 0.f, aD2 = 0.f, aD3 = 0.f;
    int e0 = s;
    for (; e0 + 32 <= e_end; e0 += 32) {
        unsigned p1 = __builtin_nontemporal_load(ep + e0 + g);
        unsigned p2 = __builtin_nontemporal_load(ep + e0 + 4 + g);
        unsigned p3 = __builtin_nontemporal_load(ep + e0 + 8 + g);
        unsigned p4 = __builtin_nontemporal_load(ep + e0 + 12 + g);
        unsigned p5 = __builtin_nontemporal_load(ep + e0 + 16 + g);
        unsigned p6 = __builtin_nontemporal_load(ep + e0 + 20 + g);
        unsigned p7 = __builtin_nontemporal_load(ep + e0 + 24 + g);
        unsigned p8 = __builtin_nontemporal_load(ep + e0 + 28 + g);
        uint2 u1 = *reinterpret_cast<const uint2*>(x_in + ((size_t)(p1 >> 15) << 6) + (li << 2));
        uint2 u2 = *reinterpret_cast<const uint2*>(x_in + ((size_t)(p2 >> 15) << 6) + (li << 2));
        uint2 u3 = *reinterpret_cast<const uint2*>(x_in + ((size_t)(p3 >> 15) << 6) + (li << 2));
        uint2 u4 = *reinterpret_cast<const uint2*>(x_in + ((size_t)(p4 >> 15) << 6) + (li << 2));
        uint2 u5 = *reinterpret_cast<const uint2*>(x_in + ((size_t)(p5 >> 15) << 6) + (li << 2));
        uint2 u6 = *reinterpret_cast<const uint2*>(x_in + ((size_t)(p6 >> 15) << 6) + (li << 2));
        uint2 u7 = *reinterpret_cast<const uint2*>(x_in + ((size_t)(p7 >> 15) << 6) + (li << 2));
        uint2 u8 = *reinterpret_cast<const uint2*>(x_in + ((size_t)(p8 >> 15) << 6) + (li << 2));
        float v1 = (float)(p1 & 0x7fffu) * (1.f / 1048576.f);
        float v2 = (float)(p2 & 0x7fffu) * (1.f / 1048576.f);
        float v3 = (float)(p3 & 0x7fffu) * (1.f / 1048576.f);
        float v4 = (float)(p4 & 0x7fffu) * (1.f / 1048576.f);
        float v5 = (float)(p5 & 0x7fffu) * (1.f / 1048576.f);
        float v6 = (float)(p6 & 0x7fffu) * (1.f / 1048576.f);
        float v7 = (float)(p7 & 0x7fffu) * (1.f / 1048576.f);
        float v8 = (float)(p8 & 0x7fffu) * (1.f / 1048576.f);
        aA0 += v1 * blo(u1.x); aA1 += v1 * bhi(u1.x);
        aA2 += v1 * blo(u1.y); aA3 += v1 * bhi(u1.y);
        aB0 += v2 * blo(u2.x); aB1 += v2 * bhi(u2.x);
        aB2 += v2 * blo(u2.y); aB3 += v2 * bhi(u2.y);
        aC0 += v3 * blo(u3.x); aC1 += v3 * bhi(u3.x);
        aC2 += v3 * blo(u3.y); aC3 += v3 * bhi(u3.y);
        aD0 += v4 * blo(u4.x); aD1 += v4 * bhi(u4.x);
        aD2 += v4 * blo(u4.y); aD3 += v4 * bhi(u4.y);
        aA0 += v5 * blo(u5.x); aA1 += v5 * bhi(u5.x);
        aA2 += v5 * blo(u5.y); aA3 += v5 * bhi(u5.y);
        aB0 += v6 * blo(u6.x); aB1 += v6 * bhi(u6.x);
        aB2 += v6 * blo(u6.y); aB3 += v6 * bhi(u6.y);
        aC0 += v7 * blo(u7.x); aC1 += v7 * bhi(u7.x);
        aC2 += v7 * blo(u7.y); aC3 += v7 * bhi(u7.y);
        aD0 += v8 * blo(u8.x); aD1 += v8 * bhi(u8.x);
        aD2 += v8 * blo(u8.y); aD3 += v8 * bhi(u8.y);
    }
    for (; e0 + 16 <= e_end; e0 += 16) {
        unsigned p1 = __builtin_nontemporal_load(ep + e0 + g);
        unsigned p2 = __builtin_nontemporal_load(ep + e0 + 4 + g);
        unsigned p3 = __builtin_nontemporal_load(ep + e0 + 8 + g);
        unsigned p4 = __builtin_nontemporal_load(ep + e0 + 12 + g);
        uint2 u1 = *reinterpret_cast<const uint2*>(x_in + ((size_t)(p1 >> 15) << 6) + (li << 2));
        uint2 u2 = *reinterpret_cast<const uint2*>(x_in + ((size_t)(p2 >> 15) << 6) + (li << 2));
        uint2 u3 = *reinterpret_cast<const uint2*>(x_in + ((size_t)(p3 >> 15) << 6) + (li << 2));
        uint2 u4 = *reinterpret_cast<const uint2*>(x_in + ((size_t)(p4 >> 15) << 6) + (li << 2));
        float v1 = (float)(p1 & 0x7fffu) * (1.f / 1048576.f);
        float v2 = (float)(p2 & 0x7fffu) * (1.f / 1048576.f);
        float v3 = (float)(p3 & 0x7fffu) * (1.f / 1048576.f);
        float v4 = (float)(p4 & 0x7fffu) * (1.f / 1048576.f);
        aA0 += v1 * blo(u1.x); aA1 += v1 * bhi(u1.x);
        aA2 += v1 * blo(u1.y); aA3 += v1 * bhi(u1.y);
        aB0 += v2 * blo(u2.x); aB1 += v2 * bhi(u2.x);
        aB2 += v2 * blo(u2.y); aB3 += v2 * bhi(u2.y);
        aC0 += v3 * blo(u3.x); aC1 += v3 * bhi(u3.x);
        aC2 += v3 * blo(u3.y); aC3 += v3 * bhi(u3.y);
        aD0 += v4 * blo(u4.x); aD1 += v4 * bhi(u4.x);
        aD2 += v4 * blo(u4.y); aD3 += v4 * bhi(u4.y);
    }
    for (; e0 < e_end; e0 += 4) {
        int e = e0 + g;
        if (e < e_end) {
            unsigned p = __builtin_nontemporal_load(ep + e);
            int   c = (int)(p >> 15);
            float v = (float)(p & 0x7fffu) * (1.f / 1048576.f);
            uint2 u = *reinterpret_cast<const uint2*>(x_in + ((size_t)c << 6) + (li << 2));
            aA0 += v * blo(u.x); aA1 += v * bhi(u.x);
            aA2 += v * blo(u.y); aA3 += v * bhi(u.y);
        }
    }
    float a0 = (aA0 + aB0) + (aC0 + aD0);
    float a1 = (aA1 + aB1) + (aC1 + aD1);
    float a2 = (aA2 + aB2) + (aC2 + aD2);
    float a3 = (aA3 + aB3) + (aC3 + aD3);
#pragma unroll
    for (int off = 16; off < 64; off <<= 1) {
        a0 += __shfl_xor(a0, off);
        a1 += __shfl_xor(a1, off);
        a2 += __shfl_xor(a2, off);
        a3 += __shfl_xor(a3, off);
    }
    if (g == 0) {
        size_t o = ((size_t)r << 6) + (li << 2);
        const unsigned* hp = reinterpret_cast<const unsigned*>(h + o);
        unsigned hx = __builtin_nontemporal_load(hp);
        unsigned hy = __builtin_nontemporal_load(hp + 1);
        float r0 = (1.f - ALPHA_C) * a0 + ALPHA_C * blo(hx);
        float r1 = (1.f - ALPHA_C) * a1 + ALPHA_C * bhi(hx);
        float r2 = (1.f - ALPHA_C) * a2 + ALPHA_C * blo(hy);
        float r3 = (1.f - ALPHA_C) * a3 + ALPHA_C * bhi(hy);
        if (LAST) {
            // fused log_softmax over the 64-ch row (lanes 0..15 hold 4 ch each)
            float m = fmaxf(fmaxf(r0, r1), fmaxf(r2, r3));
#pragma unroll
            for (int off = 1; off < 16; off <<= 1) m = fmaxf(m, __shfl_xor(m, off));
            float sum = expf(r0 - m) + expf(r1 - m) + expf(r2 - m) + expf(r3 - m);
#pragma unroll
            for (int off = 1; off < 16; off <<= 1) sum += __shfl_xor(sum, off);
            float ls = logf(sum);
            float4 ov;
            ov.x = (r0 - m) - ls;
            ov.y = (r1 - m) - ls;
            ov.z = (r2 - m) - ls;
            ov.w = (r3 - m) - ls;
            *reinterpret_cast<float4*>(out + o) = ov;
        } else {
            unsigned* op = reinterpret_cast<unsigned*>(x_out + o);
            __builtin_nontemporal_store(((unsigned)f2b(r1) << 16) | f2b(r0), op);
            __builtin_nontemporal_store(((unsigned)f2b(r3) << 16) | f2b(r2), op + 1);
        }
    }
}

extern "C" void kernel_launch(void* const* d_in, const int* in_sizes, int n_in,
                              void* d_out, int out_size, void* d_ws, size_t ws_size,
                              hipStream_t stream)
{
    const float* feat = (const float*)d_in[0];
    const float* W1   = (const float*)d_in[1];
    const float* b1   = (const float*)d_in[2];
    const float* W2   = (const float*)d_in[3];
    const float* b2   = (const float*)d_in[4];
    const float* vals = (const float*)d_in[5];
    const int*   erow = (const int*)d_in[6];
    const int*   ecol = (const int*)d_in[7];
    const int N = in_sizes[0] / NFEAT;
    const int E = in_sizes[5];
    float* out = (float*)d_out;
    const int CE = (E + NPB - 1) / NPB;
    const int NC = NBUCKET * NPB;

    size_t off = 0;
    auto alloc = [&](size_t bytes) -> void* {
        void* p = (char*)d_ws + off;
        off += (bytes + 255) & ~(size_t)255;
        return p;
    };
    unsigned short*     h        = (unsigned short*)alloc((size_t)N * NCLS * 2);
    unsigned short*     xA       = (unsigned short*)alloc((size_t)N * NCLS * 2);
    unsigned short*     xB       = (unsigned short*)alloc((size_t)N * NCLS * 2);
    int*                row_ptr  = (int*)alloc((size_t)(N + 1) * 4);
    int*                cnts     = (int*)alloc((size_t)NC * 4);
    int*                S        = (int*)alloc((size_t)(NC + 1) * 4);
    int*                partials = (int*)alloc(256 * 4);
    unsigned*           ep       = (unsigned*)alloc((size_t)E * 4);
    unsigned long long* stage    = (unsigned long long*)alloc((size_t)E * 8);
    unsigned short*     W1T      = (unsigned short*)alloc((size_t)NHID * NFEAT * 2);
    unsigned short*     W2T      = (unsigned short*)alloc((size_t)NCLS * NHID * 2);
    (void)ws_size;

    // 0. weight transpose+convert (tiny)
    cvtT_kernel<<<(NFEAT * NHID + 255) / 256, 256, 0, stream>>>(W1, W1T, NFEAT, 8);
    cvtT_kernel<<<(NHID * NCLS + 255) / 256, 256, 0, stream>>>(W2, W2T, NHID, 6);

    // 1. fused MFMA MLP (fp32 feat, HW packed cvt -- no featb pass)
    mlp_mfma_kernel<<<(N + 63) / 64, 256, 0, stream>>>(feat, W1T, b1, W2T, b2, h, N);

    // 2. 2-level scatter -> CSR (round-8 proven)
    countP1_kernel<<<NPB, 256, 0, stream>>>(erow, cnts, E, CE);
    scanA_kernel<<<NC / 1024, 1024, 0, stream>>>(cnts, S, partials, NC);
    scanB_kernel<<<1, 256, 0, stream>>>(partials, S, 256, NC);
    scanC_kernel<<<NC / 1024, 1024, 0, stream>>>(S, partials, NC);
    scatterA_kernel<<<NPB, 256, 0, stream>>>(vals, erow, ecol, S, stage, E, CE);
    scatterB_kernel<<<NBUCKET, 256, 0, stream>>>(stage, S, ep, row_ptr, N, E);

    // 3. K=10 propagation; iteration 10 fuses log_softmax and writes d_out
    const int gprop = (N + 3) / 4;
    const unsigned short* cur = h;
    for (int i = 0; i < 9; ++i) {
        unsigned short* dst = (i & 1) ? xB : xA;
        spmm_kernel<0><<<gprop, 256, 0, stream>>>(cur, h, dst, nullptr, row_ptr, ep, N);
        cur = dst;
    }
    spmm_kernel<1><<<gprop, 256, 0, stream>>>(cur, h, nullptr, out, row_ptr, ep, N);
}

// Round 16
// 1052.708 us; speedup vs baseline: 1.0132x; 1.0132x over previous
//
#include <hip/hip_runtime.h>
#include <hip/hip_bf16.h>
#include <math.h>

#define NNODES 100000
#define NFEAT 512
#define NHID 256
#define NCLS 64
#define ALPHA_C 0.1f
#define NBUCKET 512   // coarse row-buckets for 2-level scatter
#define NPB 512       // partition blocks (edge chunks)
#define RB2 196       // rows per bucket: ceil(100000/512)

typedef short s16x8 __attribute__((ext_vector_type(8)));
typedef float f32x4 __attribute__((ext_vector_type(4)));

__device__ inline unsigned short f2b(float f) {
    union { float f; unsigned u; } v; v.f = f;
    unsigned r = v.u + 0x7fff + ((v.u >> 16) & 1);   // RNE
    return (unsigned short)(r >> 16);
}
__device__ inline float b2f(unsigned short b) {
    return __uint_as_float((unsigned)b << 16);
}
__device__ inline float blo(unsigned u) { return __uint_as_float(u << 16); }
__device__ inline float bhi(unsigned u) { return __uint_as_float(u & 0xffff0000u); }

// ---------------- transpose+convert: dst[C][R] bf16 <- src[R][C] fp32 ----------------
__global__ __launch_bounds__(256) void cvtT_kernel(
    const float* __restrict__ src, unsigned short* __restrict__ dst, int R, int Clog2)
{
    int idx = blockIdx.x * 256 + threadIdx.x;
    int C = 1 << Clog2;
    if (idx < R * C) {
        int r = idx >> Clog2, c = idx & (C - 1);
        dst[(size_t)c * R + r] = f2b(src[idx]);
    }
}

// ---------------- streaming convert: feat fp32 -> bf16 (same layout) ----------------
__global__ __launch_bounds__(256) void cvtF_kernel(
    const float* __restrict__ src, unsigned short* __restrict__ dst, long n8)
{
    long i = (long)blockIdx.x * 256 + threadIdx.x;
    if (i < n8) {
        const float4* s = reinterpret_cast<const float4*>(src + i * 8);
        float4 f0 = s[0], f1 = s[1];
        s16x8 a;
        a[0] = f2b(f0.x); a[1] = f2b(f0.y); a[2] = f2b(f0.z); a[3] = f2b(f0.w);
        a[4] = f2b(f1.x); a[5] = f2b(f1.y); a[6] = f2b(f1.z); a[7] = f2b(f1.w);
        *reinterpret_cast<s16x8*>(dst + i * 8) = a;
    }
}

// ---------------- fused MFMA MLP (fp32-feat fallback): h = relu(f@W1+b1)@W2+b2 -------
#define HID_STRIDE 264   // 256 + 8 pad

__global__ __launch_bounds__(256) void mlp_mfma_kernel(
    const float* __restrict__ feat, const unsigned short* __restrict__ W1T,
    const float* __restrict__ b1, const unsigned short* __restrict__ W2T,
    const float* __restrict__ b2, unsigned short* __restrict__ h, int N)
{
    __shared__ unsigned short hid_s[64 * HID_STRIDE];
    const int tid  = threadIdx.x;
    const int w    = tid >> 6;
    const int lane = tid & 63;
    const int lr   = lane & 15;
    const int lh   = lane >> 4;
    const int m0   = blockIdx.x * 64;

    f32x4 acc[4][4];
#pragma unroll
    for (int i = 0; i < 4; ++i)
#pragma unroll
        for (int j = 0; j < 4; ++j) acc[i][j] = (f32x4)0.f;

    const float* arow[4];
#pragma unroll
    for (int mi = 0; mi < 4; ++mi) {
        int r = m0 + mi * 16 + lr;
        if (r > N - 1) r = N - 1;
        arow[mi] = feat + (size_t)r * NFEAT;
    }
    const unsigned short* brow[4];
#pragma unroll
    for (int nj = 0; nj < 4; ++nj)
        brow[nj] = W1T + (size_t)(w * 64 + nj * 16 + lr) * NFEAT;

    for (int kb = 0; kb < NFEAT; kb += 32) {
        const int k0 = kb + lh * 8;
        s16x8 afr[4], bfr[4];
#pragma unroll
        for (int mi = 0; mi < 4; ++mi) {
            float4 f0 = *reinterpret_cast<const float4*>(arow[mi] + k0);
            float4 f1 = *reinterpret_cast<const float4*>(arow[mi] + k0 + 4);
            s16x8 a;
            a[0] = f2b(f0.x); a[1] = f2b(f0.y); a[2] = f2b(f0.z); a[3] = f2b(f0.w);
            a[4] = f2b(f1.x); a[5] = f2b(f1.y); a[6] = f2b(f1.z); a[7] = f2b(f1.w);
            afr[mi] = a;
        }
#pragma unroll
        for (int nj = 0; nj < 4; ++nj)
            bfr[nj] = *reinterpret_cast<const s16x8*>(brow[nj] + k0);
#pragma unroll
        for (int mi = 0; mi < 4; ++mi)
#pragma unroll
            for (int nj = 0; nj < 4; ++nj)
                acc[mi][nj] = __builtin_amdgcn_mfma_f32_16x16x32_bf16(
                    afr[mi], bfr[nj], acc[mi][nj], 0, 0, 0);
    }

#pragma unroll
    for (int nj = 0; nj < 4; ++nj) {
        int col = w * 64 + nj * 16 + lr;
        float bias = b1[col];
#pragma unroll
        for (int mi = 0; mi < 4; ++mi)
#pragma unroll
            for (int q = 0; q < 4; ++q) {
                int row = mi * 16 + lh * 4 + q;
                hid_s[row * HID_STRIDE + col] = f2b(fmaxf(acc[mi][nj][q] + bias, 0.f));
            }
    }
    __syncthreads();

    f32x4 acc2[4];
#pragma unroll
    for (int i = 0; i < 4; ++i) acc2[i] = (f32x4)0.f;
    const int cw = w * 16;
    const unsigned short* b2row = W2T + (size_t)(cw + lr) * NHID;
    for (int ks = 0; ks < NHID; ks += 32) {
        int k0 = ks + lh * 8;
        s16x8 bfr = *reinterpret_cast<const s16x8*>(b2row + k0);
#pragma unroll
        for (int mi = 0; mi < 4; ++mi) {
            s16x8 afr = *reinterpret_cast<const s16x8*>(
                &hid_s[(mi * 16 + lr) * HID_STRIDE + k0]);
            acc2[mi] = __builtin_amdgcn_mfma_f32_16x16x32_bf16(afr, bfr, acc2[mi], 0, 0, 0);
        }
    }
    int col = cw + lr;
    float bias2 = b2[col];
#pragma unroll
    for (int mi = 0; mi < 4; ++mi)
#pragma unroll
        for (int q = 0; q < 4; ++q) {
            int row = m0 + mi * 16 + lh * 4 + q;
            if (row < N) h[(size_t)row * NCLS + col] = f2b(acc2[mi][q] + bias2);
        }
}

// ---------------- fused MFMA MLP (bf16-feat fast path) ----------------
__global__ __launch_bounds__(256) void mlp_mfma_bf16_kernel(
    const unsigned short* __restrict__ feat, const unsigned short* __restrict__ W1T,
    const float* __restrict__ b1, const unsigned short* __restrict__ W2T,
    const float* __restrict__ b2, unsigned short* __restrict__ h, int N)
{
    __shared__ unsigned short hid_s[64 * HID_STRIDE];
    const int tid  = threadIdx.x;
    const int w    = tid >> 6;
    const int lane = tid & 63;
    const int lr   = lane & 15;
    const int lh   = lane >> 4;
    const int m0   = blockIdx.x * 64;

    f32x4 acc[4][4];
#pragma unroll
    for (int i = 0; i < 4; ++i)
#pragma unroll
        for (int j = 0; j < 4; ++j) acc[i][j] = (f32x4)0.f;

    const unsigned short* arow[4];
#pragma unroll
    for (int mi = 0; mi < 4; ++mi) {
        int r = m0 + mi * 16 + lr;
        if (r > N - 1) r = N - 1;
        arow[mi] = feat + (size_t)r * NFEAT;
    }
    const unsigned short* brow[4];
#pragma unroll
    for (int nj = 0; nj < 4; ++nj)
        brow[nj] = W1T + (size_t)(w * 64 + nj * 16 + lr) * NFEAT;

    for (int kb = 0; kb < NFEAT; kb += 32) {
        const int k0 = kb + lh * 8;
        s16x8 afr[4], bfr[4];
#pragma unroll
        for (int mi = 0; mi < 4; ++mi)
            afr[mi] = *reinterpret_cast<const s16x8*>(arow[mi] + k0);
#pragma unroll
        for (int nj = 0; nj < 4; ++nj)
            bfr[nj] = *reinterpret_cast<const s16x8*>(brow[nj] + k0);
#pragma unroll
        for (int mi = 0; mi < 4; ++mi)
#pragma unroll
            for (int nj = 0; nj < 4; ++nj)
                acc[mi][nj] = __builtin_amdgcn_mfma_f32_16x16x32_bf16(
                    afr[mi], bfr[nj], acc[mi][nj], 0, 0, 0);
    }

#pragma unroll
    for (int nj = 0; nj < 4; ++nj) {
        int col = w * 64 + nj * 16 + lr;
        float bias = b1[col];
#pragma unroll
        for (int mi = 0; mi < 4; ++mi)
#pragma unroll
            for (int q = 0; q < 4; ++q) {
                int row = mi * 16 + lh * 4 + q;
                hid_s[row * HID_STRIDE + col] = f2b(fmaxf(acc[mi][nj][q] + bias, 0.f));
            }
    }
    __syncthreads();

    f32x4 acc2[4];
#pragma unroll
    for (int i = 0; i < 4; ++i) acc2[i] = (f32x4)0.f;
    const int cw = w * 16;
    const unsigned short* b2row = W2T + (size_t)(cw + lr) * NHID;
    for (int ks = 0; ks < NHID; ks += 32) {
        int k0 = ks + lh * 8;
        s16x8 bfr = *reinterpret_cast<const s16x8*>(b2row + k0);
#pragma unroll
        for (int mi = 0; mi < 4; ++mi) {
            s16x8 afr = *reinterpret_cast<const s16x8*>(
                &hid_s[(mi * 16 + lr) * HID_STRIDE + k0]);
            acc2[mi] = __builtin_amdgcn_mfma_f32_16x16x32_bf16(afr, bfr, acc2[mi], 0, 0, 0);
        }
    }
    int col = cw + lr;
    float bias2 = b2[col];
#pragma unroll
    for (int mi = 0; mi < 4; ++mi)
#pragma unroll
        for (int q = 0; q < 4; ++q) {
            int row = m0 + mi * 16 + lh * 4 + q;
            if (row < N) h[(size_t)row * NCLS + col] = f2b(acc2[mi][q] + bias2);
        }
}

// ---------------- 3-phase scan ----------------
__global__ __launch_bounds__(1024) void scanA_kernel(
    const int* __restrict__ cnt, int* __restrict__ excl, int* __restrict__ partials, int n)
{
    __shared__ int wsum[16];
    const int t = threadIdx.x, wid = t >> 6, lane = t & 63;
    const int i = blockIdx.x * 1024 + t;
    int c = (i < n) ? cnt[i] : 0;
    int x = c;
#pragma unroll
    for (int off = 1; off < 64; off <<= 1) {
        int y = __shfl_up(x, off);
        if (lane >= off) x += y;
    }
    if (lane == 63) wsum[wid] = x;
    __syncthreads();
    if (wid == 0 && lane < 16) {
        int wv = wsum[lane];
#pragma unroll
        for (int off = 1; off < 16; off <<= 1) {
            int y = __shfl_up(wv, off);
            if (lane >= off) wv += y;
        }
        wsum[lane] = wv;
    }
    __syncthreads();
    int woff = wid ? wsum[wid - 1] : 0;
    int incl = x + woff;
    if (i < n) excl[i] = incl - c;
    if (t == 1023) partials[blockIdx.x] = incl;
}

__global__ __launch_bounds__(256) void scanB_kernel(
    int* __restrict__ partials, int* __restrict__ total_out, int nb, int n)
{
    __shared__ int s[256];
    const int t = threadIdx.x;
    int v = (t < nb) ? partials[t] : 0;
    s[t] = v;
    __syncthreads();
    for (int off = 1; off < 256; off <<= 1) {
        int y = (t >= off) ? s[t - off] : 0;
        __syncthreads();
        s[t] += y;
        __syncthreads();
    }
    partials[t] = s[t] - v;
    if (t == 255) total_out[n] = s[255];
}

__global__ __launch_bounds__(1024) void scanC_kernel(
    int* __restrict__ arr, const int* __restrict__ partials, int n)
{
    const int i = blockIdx.x * 1024 + threadIdx.x;
    if (i < n) arr[i] += partials[blockIdx.x];
}

// ------------- 2-level scatter (round-8 proven) -------------
__global__ __launch_bounds__(256) void countP1_kernel(
    const int* __restrict__ erow, int* __restrict__ cnts, int E, int CE)
{
    __shared__ int c[NBUCKET];
    const int blk = blockIdx.x, t = threadIdx.x;
    for (int i = t; i < NBUCKET; i += 256) c[i] = 0;
    __syncthreads();
    const int e0 = blk * CE, e1 = min(e0 + CE, E);
    for (int e = e0 + t; e < e1; e += 256)
        atomicAdd(&c[erow[e] / RB2], 1);
    __syncthreads();
    for (int b = t; b < NBUCKET; b += 256)
        cnts[(size_t)b * NPB + blk] = c[b];
}

__global__ __launch_bounds__(256) void scatterA_kernel(
    const float* __restrict__ vals, const int* __restrict__ erow,
    const int* __restrict__ ecol, const int* __restrict__ S,
    unsigned long long* __restrict__ stage, int E, int CE)
{
    __shared__ int lcur[NBUCKET];
    const int blk = blockIdx.x, t = threadIdx.x;
    for (int b = t; b < NBUCKET; b += 256) lcur[b] = S[(size_t)b * NPB + blk];
    __syncthreads();
    const int e0 = blk * CE, e1 = min(e0 + CE, E);
    for (int e = e0 + t; e < e1; e += 256) {
        int r = erow[e];
        unsigned q = (unsigned)__float2int_rn(vals[e] * 1048576.f);
        if (q > 32767u) q = 32767u;
        unsigned lo = ((unsigned)ecol[e] << 15) | q;
        int pos = atomicAdd(&lcur[r / RB2], 1);
        stage[pos] = ((unsigned long long)(unsigned)r << 32) | lo;
    }
}

__global__ __launch_bounds__(256) void scatterB_kernel(
    const unsigned long long* __restrict__ stage, const int* __restrict__ S,
    unsigned* __restrict__ ep, int* __restrict__ row_ptr, int n, int E)
{
    __shared__ int hcnt[256];
    __shared__ int lcur[256];
    const int b = blockIdx.x, t = threadIdx.x;
    if (b == 0 && t == 0) row_ptr[n] = E;
    const int r0 = b * RB2;
    if (r0 >= n) return;
    const int nr = min(RB2, n - r0);
    const int s0 = S[(size_t)b * NPB];
    const int s1 = S[(size_t)(b + 1) * NPB];
    hcnt[t] = 0;
    __syncthreads();
    for (int i = s0 + t; i < s1; i += 256)
        atomicAdd(&hcnt[(int)(stage[i] >> 32) - r0], 1);
    __syncthreads();
    int v = hcnt[t];
    lcur[t] = v;
    __syncthreads();
    for (int off = 1; off < 256; off <<= 1) {
        int y = (t >= off) ? lcur[t - off] : 0;
        __syncthreads();
        lcur[t] += y;
        __syncthreads();
    }
    int excl = lcur[t] - v;
    if (t < nr) row_ptr[r0 + t] = s0 + excl;
    __syncthreads();
    lcur[t] = s0 + excl;
    __syncthreads();
    for (int i = s0 + t; i < s1; i += 256) {
        unsigned long long rec = stage[i];
        int r = (int)(rec >> 32);
        int p = atomicAdd(&lcur[r - r0], 1);
        ep[p] = (unsigned)rec;
    }
}

// ------- SPMM + APPNP update (bf16 state): x_out = 0.9*A*x_in + 0.1*h -------
// wave = 4 edge-groups x 16 lanes; 32-edge superstep. LAST=1 fuses log_softmax.
template<int LAST>
__global__ __launch_bounds__(256) void spmm_kernel(
    const unsigned short* __restrict__ x_in, const unsigned short* __restrict__ h,
    unsigned short* __restrict__ x_out, float* __restrict__ out,
    const int* __restrict__ row_ptr, const unsigned* __restrict__ ep, int n)
{
    const int wid = threadIdx.x >> 6, lane = threadIdx.x & 63;
    const int r = blockIdx.x * 4 + wid;
    if (r >= n) return;
    const int g  = lane >> 4;
    const int li = lane & 15;
    const int s = row_ptr[r], e_end = row_ptr[r + 1];

    float aA0 = 0.f, aA1 = 0.f, aA2 = 0.f, aA3 = 0.f;
    float aB0 = 0.f, aB1 = 0.f, aB2 = 0.f, aB3 = 0.f;
    float aC0 = 0.f, aC1 = 0.f, aC2 = 0.f, aC3 = 0.f;
    float aD0 = 0.f, aD1 = 0.f, aD2 = 0.f, aD3 = 0.f;
    int e0 = s;
    for (; e0 + 32 <= e_end; e0 += 32) {
        unsigned p1 = __builtin_nontemporal_load(ep + e0 + g);
        unsigned p2 = __builtin_nontemporal_load(ep + e0 + 4 + g);
        unsigned p3 = __builtin_nontemporal_load(ep + e0 + 8 + g);
        unsigned p4 = __builtin_nontemporal_load(ep + e0 + 12 + g);
        unsigned p5 = __builtin_nontemporal_load(ep + e0 + 16 + g);
        unsigned p6 = __builtin_nontemporal_load(ep + e0 + 20 + g);
        unsigned p7 = __builtin_nontemporal_load(ep + e0 + 24 + g);
        unsigned p8 = __builtin_nontemporal_load(ep + e0 + 28 + g);
        uint2 u1 = *reinterpret_cast<const uint2*>(x_in + ((size_t)(p1 >> 15) << 6) + (li << 2));
        uint2 u2 = *reinterpret_cast<const uint2*>(x_in + ((size_t)(p2 >> 15) << 6) + (li << 2));
        uint2 u3 = *reinterpret_cast<const uint2*>(x_in + ((size_t)(p3 >> 15) << 6) + (li << 2));
        uint2 u4 = *reinterpret_cast<const uint2*>(x_in + ((size_t)(p4 >> 15) << 6) + (li << 2));
        uint2 u5 = *reinterpret_cast<const uint2*>(x_in + ((size_t)(p5 >> 15) << 6) + (li << 2));
        uint2 u6 = *reinterpret_cast<const uint2*>(x_in + ((size_t)(p6 >> 15) << 6) + (li << 2));
        uint2 u7 = *reinterpret_cast<const uint2*>(x_in + ((size_t)(p7 >> 15) << 6) + (li << 2));
        uint2 u8 = *reinterpret_cast<const uint2*>(x_in + ((size_t)(p8 >> 15) << 6) + (li << 2));
        float v1 = (float)(p1 & 0x7fffu) * (1.f / 1048576.f);
        float v2 = (float)(p2 & 0x7fffu) * (1.f / 1048576.f);
        float v3 = (float)(p3 & 0x7fffu) * (1.f / 1048576.f);
        float v4 = (float)(p4 & 0x7fffu) * (1.f / 1048576.f);
        float v5 = (float)(p5 & 0x7fffu) * (1.f / 1048576.f);
        float v6 = (float)(p6 & 0x7fffu) * (1.f / 1048576.f);
        float v7 = (float)(p7 & 0x7fffu) * (1.f / 1048576.f);
        float v8 = (float)(p8 & 0x7fffu) * (1.f / 1048576.f);
        aA0 += v1 * blo(u1.x); aA1 += v1 * bhi(u1.x);
        aA2 += v1 * blo(u1.y); aA3 += v1 * bhi(u1.y);
        aB0 += v2 * blo(u2.x); aB1 += v2 * bhi(u2.x);
        aB2 += v2 * blo(u2.y); aB3 += v2 * bhi(u2.y);
        aC0 += v3 * blo(u3.x); aC1 += v3 * bhi(u3.x);
        aC2 += v3 * blo(u3.y); aC3 += v3 * bhi(u3.y);
        aD0 += v4 * blo(u4.x); aD1 += v4 * bhi(u4.x);
        aD2 += v4 * blo(u4.y); aD3 += v4 * bhi(u4.y);
        aA0 += v5 * blo(u5.x); aA1 += v5 * bhi(u5.x);
        aA2 += v5 * blo(u5.y); aA3 += v5 * bhi(u5.y);
        aB0 += v6 * blo(u6.x); aB1 += v6 * bhi(u6.x);
        aB2 += v6 * blo(u6.y); aB3 += v6 * bhi(u6.y);
        aC0 += v7 * blo(u7.x); aC1 += v7 * bhi(u7.x);
        aC2 += v7 * blo(u7.y); aC3 += v7 * bhi(u7.y);
        aD0 += v8 * blo(u8.x); aD1 += v8 * bhi(u8.x);
        aD2 += v8 * blo(u8.y); aD3 += v8 * bhi(u8.y);
    }
    for (; e0 + 16 <= e_end; e0 += 16) {
        unsigned p1 = __builtin_nontemporal_load(ep + e0 + g);
        unsigned p2 = __builtin_nontemporal_load(ep + e0 + 4 + g);
        unsigned p3 = __builtin_nontemporal_load(ep + e0 + 8 + g);
        unsigned p4 = __builtin_nontemporal_load(ep + e0 + 12 + g);
        uint2 u1 = *reinterpret_cast<const uint2*>(x_in + ((size_t)(p1 >> 15) << 6) + (li << 2));
        uint2 u2 = *reinterpret_cast<const uint2*>(x_in + ((size_t)(p2 >> 15) << 6) + (li << 2));
        uint2 u3 = *reinterpret_cast<const uint2*>(x_in + ((size_t)(p3 >> 15) << 6) + (li << 2));
        uint2 u4 = *reinterpret_cast<const uint2*>(x_in + ((size_t)(p4 >> 15) << 6) + (li << 2));
        float v1 = (float)(p1 & 0x7fffu) * (1.f / 1048576.f);
        float v2 = (float)(p2 & 0x7fffu) * (1.f / 1048576.f);
        float v3 = (float)(p3 & 0x7fffu) * (1.f / 1048576.f);
        float v4 = (float)(p4 & 0x7fffu) * (1.f / 1048576.f);
        aA0 += v1 * blo(u1.x); aA1 += v1 * bhi(u1.x);
        aA2 += v1 * blo(u1.y); aA3 += v1 * bhi(u1.y);
        aB0 += v2 * blo(u2.x); aB1 += v2 * bhi(u2.x);
        aB2 += v2 * blo(u2.y); aB3 += v2 * bhi(u2.y);
        aC0 += v3 * blo(u3.x); aC1 += v3 * bhi(u3.x);
        aC2 += v3 * blo(u3.y); aC3 += v3 * bhi(u3.y);
        aD0 += v4 * blo(u4.x); aD1 += v4 * bhi(u4.x);
        aD2 += v4 * blo(u4.y); aD3 += v4 * bhi(u4.y);
    }
    for (; e0 < e_end; e0 += 4) {
        int e = e0 + g;
        if (e < e_end) {
            unsigned p = __builtin_nontemporal_load(ep + e);
            int   c = (int)(p >> 15);
            float v = (float)(p & 0x7fffu) * (1.f / 1048576.f);
            uint2 u = *reinterpret_cast<const uint2*>(x_in + ((size_t)c << 6) + (li << 2));
            aA0 += v * blo(u.x); aA1 += v * bhi(u.x);
            aA2 += v * blo(u.y); aA3 += v * bhi(u.y);
        }
    }
    float a0 = (aA0 + aB0) + (aC0 + aD0);
    float a1 = (aA1 + aB1) + (aC1 + aD1);
    float a2 = (aA2 + aB2) + (aC2 + aD2);
    float a3 = (aA3 + aB3) + (aC3 + aD3);
#pragma unroll
    for (int off = 16; off < 64; off <<= 1) {
        a0 += __shfl_xor(a0, off);
        a1 += __shfl_xor(a1, off);
        a2 += __shfl_xor(a2, off);
        a3 += __shfl_xor(a3, off);
    }
    if (g == 0) {
        size_t o = ((size_t)r << 6) + (li << 2);
        const unsigned* hp = reinterpret_cast<const unsigned*>(h + o);
        unsigned hx = __builtin_nontemporal_load(hp);
        unsigned hy = __builtin_nontemporal_load(hp + 1);
        float r0 = (1.f - ALPHA_C) * a0 + ALPHA_C * blo(hx);
        float r1 = (1.f - ALPHA_C) * a1 + ALPHA_C * bhi(hx);
        float r2 = (1.f - ALPHA_C) * a2 + ALPHA_C * blo(hy);
        float r3 = (1.f - ALPHA_C) * a3 + ALPHA_C * bhi(hy);
        if (LAST) {
            float m = fmaxf(fmaxf(r0, r1), fmaxf(r2, r3));
#pragma unroll
            for (int off = 1; off < 16; off <<= 1) m = fmaxf(m, __shfl_xor(m, off));
            float sum = expf(r0 - m) + expf(r1 - m) + expf(r2 - m) + expf(r3 - m);
#pragma unroll
            for (int off = 1; off < 16; off <<= 1) sum += __shfl_xor(sum, off);
            float ls = logf(sum);
            float4 ov;
            ov.x = (r0 - m) - ls;
            ov.y = (r1 - m) - ls;
            ov.z = (r2 - m) - ls;
            ov.w = (r3 - m) - ls;
            *reinterpret_cast<float4*>(out + o) = ov;
        } else {
            unsigned* op = reinterpret_cast<unsigned*>(x_out + o);
            __builtin_nontemporal_store(((unsigned)f2b(r1) << 16) | f2b(r0), op);
            __builtin_nontemporal_store(((unsigned)f2b(r3) << 16) | f2b(r2), op + 1);
        }
    }
}

extern "C" void kernel_launch(void* const* d_in, const int* in_sizes, int n_in,
                              void* d_out, int out_size, void* d_ws, size_t ws_size,
                              hipStream_t stream)
{
    const float* feat = (const float*)d_in[0];
    const float* W1   = (const float*)d_in[1];
    const float* b1   = (const float*)d_in[2];
    const float* W2   = (const float*)d_in[3];
    const float* b2   = (const float*)d_in[4];
    const float* vals = (const float*)d_in[5];
    const int*   erow = (const int*)d_in[6];
    const int*   ecol = (const int*)d_in[7];
    const int N = in_sizes[0] / NFEAT;
    const int E = in_sizes[5];
    float* out = (float*)d_out;
    const int CE = (E + NPB - 1) / NPB;
    const int NC = NBUCKET * NPB;

    size_t off = 0;
    auto alloc = [&](size_t bytes) -> void* {
        void* p = (char*)d_ws + off;
        off += (bytes + 255) & ~(size_t)255;
        return p;
    };
    unsigned short*     h        = (unsigned short*)alloc((size_t)N * NCLS * 2);
    unsigned short*     xA       = (unsigned short*)alloc((size_t)N * NCLS * 2);
    unsigned short*     xB       = (unsigned short*)alloc((size_t)N * NCLS * 2);
    int*                row_ptr  = (int*)alloc((size_t)(N + 1) * 4);
    int*                cnts     = (int*)alloc((size_t)NC * 4);
    int*                S        = (int*)alloc((size_t)(NC + 1) * 4);
    int*                partials = (int*)alloc(256 * 4);
    unsigned*           ep       = (unsigned*)alloc((size_t)E * 4);
    unsigned long long* stage    = (unsigned long long*)alloc((size_t)E * 8);
    unsigned short*     W1T      = (unsigned short*)alloc((size_t)NHID * NFEAT * 2);
    unsigned short*     W2T      = (unsigned short*)alloc((size_t)NCLS * NHID * 2);
    // optional fast-path buffer (102.4 MB) -- only used if ws is big enough
    size_t off_before_featb = off;
    unsigned short*     featb    = (unsigned short*)alloc((size_t)N * NFEAT * 2);
    const bool use_bf16_feat = (off <= ws_size);
    if (!use_bf16_feat) off = off_before_featb;

    // 0. weight transpose+convert (tiny)
    cvtT_kernel<<<(NFEAT * NHID + 255) / 256, 256, 0, stream>>>(W1, W1T, NFEAT, 8);
    cvtT_kernel<<<(NHID * NCLS + 255) / 256, 256, 0, stream>>>(W2, W2T, NHID, 6);

    // 1. MLP: bf16-feat fast path when ws permits (two-pass beats fused cvt: R15)
    if (use_bf16_feat) {
        const long n8 = (long)N * NFEAT / 8;
        cvtF_kernel<<<(int)((n8 + 255) / 256), 256, 0, stream>>>(feat, featb, n8);
        mlp_mfma_bf16_kernel<<<(N + 63) / 64, 256, 0, stream>>>(featb, W1T, b1, W2T, b2, h, N);
    } else {
        mlp_mfma_kernel<<<(N + 63) / 64, 256, 0, stream>>>(feat, W1T, b1, W2T, b2, h, N);
    }

    // 2. 2-level scatter -> CSR (round-8 proven)
    countP1_kernel<<<NPB, 256, 0, stream>>>(erow, cnts, E, CE);
    scanA_kernel<<<NC / 1024, 1024, 0, stream>>>(cnts, S, partials, NC);
    scanB_kernel<<<1, 256, 0, stream>>>(partials, S, 256, NC);
    scanC_kernel<<<NC / 1024, 1024, 0, stream>>>(S, partials, NC);
    scatterA_kernel<<<NPB, 256, 0, stream>>>(vals, erow, ecol, S, stage, E, CE);
    scatterB_kernel<<<NBUCKET, 256, 0, stream>>>(stage, S, ep, row_ptr, N, E);

    // 3. K=10 propagation; iteration 10 fuses log_softmax and writes d_out
    const int gprop = (N + 3) / 4;
    const unsigned short* cur = h;
    for (int i = 0; i < 9; ++i) {
        unsigned short* dst = (i & 1) ? xB : xA;
        spmm_kernel<0><<<gprop, 256, 0, stream>>>(cur, h, dst, nullptr, row_ptr, ep, N);
        cur = dst;
    }
    spmm_kernel<1><<<gprop, 256, 0, stream>>>(cur, h, nullptr, out, row_ptr, ep, N);
}

// Round 18
// 1049.915 us; speedup vs baseline: 1.0159x; 1.0027x over previous
//
#include <hip/hip_runtime.h>
#include <hip/hip_bf16.h>
#include <math.h>

#define NNODES 100000
#define NFEAT 512
#define NHID 256
#define NCLS 64
#define ALPHA_C 0.1f
#define NBUCKET 512   // coarse row-buckets for 2-level scatter
#define NPB 512       // partition blocks (edge chunks)
#define RB2 196       // rows per bucket: ceil(100000/512)

typedef short s16x8 __attribute__((ext_vector_type(8)));
typedef float f32x4 __attribute__((ext_vector_type(4)));

__device__ inline unsigned short f2b(float f) {
    union { float f; unsigned u; } v; v.f = f;
    unsigned r = v.u + 0x7fff + ((v.u >> 16) & 1);   // RNE
    return (unsigned short)(r >> 16);
}
__device__ inline float b2f(unsigned short b) {
    return __uint_as_float((unsigned)b << 16);
}
__device__ inline float blo(unsigned u) { return __uint_as_float(u << 16); }
__device__ inline float bhi(unsigned u) { return __uint_as_float(u & 0xffff0000u); }

// ---------------- transpose+convert: dst[C][R] bf16 <- src[R][C] fp32 ----------------
__global__ __launch_bounds__(256) void cvtT_kernel(
    const float* __restrict__ src, unsigned short* __restrict__ dst, int R, int Clog2)
{
    int idx = blockIdx.x * 256 + threadIdx.x;
    int C = 1 << Clog2;
    if (idx < R * C) {
        int r = idx >> Clog2, c = idx & (C - 1);
        dst[(size_t)c * R + r] = f2b(src[idx]);
    }
}

// ---------------- streaming convert: feat fp32 -> bf16 (same layout) ----------------
__global__ __launch_bounds__(256) void cvtF_kernel(
    const float* __restrict__ src, unsigned short* __restrict__ dst, long n8)
{
    long i = (long)blockIdx.x * 256 + threadIdx.x;
    if (i < n8) {
        const float4* s = reinterpret_cast<const float4*>(src + i * 8);
        float4 f0 = s[0], f1 = s[1];
        s16x8 a;
        a[0] = f2b(f0.x); a[1] = f2b(f0.y); a[2] = f2b(f0.z); a[3] = f2b(f0.w);
        a[4] = f2b(f1.x); a[5] = f2b(f1.y); a[6] = f2b(f1.z); a[7] = f2b(f1.w);
        *reinterpret_cast<s16x8*>(dst + i * 8) = a;
    }
}

// ---------------- fused MFMA MLP (fp32-feat fallback): h = relu(f@W1+b1)@W2+b2 -------
#define HID_STRIDE 264   // 256 + 8 pad

__global__ __launch_bounds__(256) void mlp_mfma_kernel(
    const float* __restrict__ feat, const unsigned short* __restrict__ W1T,
    const float* __restrict__ b1, const unsigned short* __restrict__ W2T,
    const float* __restrict__ b2, unsigned short* __restrict__ h, int N)
{
    __shared__ unsigned short hid_s[64 * HID_STRIDE];
    const int tid  = threadIdx.x;
    const int w    = tid >> 6;
    const int lane = tid & 63;
    const int lr   = lane & 15;
    const int lh   = lane >> 4;
    const int m0   = blockIdx.x * 64;

    f32x4 acc[4][4];
#pragma unroll
    for (int i = 0; i < 4; ++i)
#pragma unroll
        for (int j = 0; j < 4; ++j) acc[i][j] = (f32x4)0.f;

    const float* arow[4];
#pragma unroll
    for (int mi = 0; mi < 4; ++mi) {
        int r = m0 + mi * 16 + lr;
        if (r > N - 1) r = N - 1;
        arow[mi] = feat + (size_t)r * NFEAT;
    }
    const unsigned short* brow[4];
#pragma unroll
    for (int nj = 0; nj < 4; ++nj)
        brow[nj] = W1T + (size_t)(w * 64 + nj * 16 + lr) * NFEAT;

    for (int kb = 0; kb < NFEAT; kb += 32) {
        const int k0 = kb + lh * 8;
        s16x8 afr[4], bfr[4];
#pragma unroll
        for (int mi = 0; mi < 4; ++mi) {
            float4 f0 = *reinterpret_cast<const float4*>(arow[mi] + k0);
            float4 f1 = *reinterpret_cast<const float4*>(arow[mi] + k0 + 4);
            s16x8 a;
            a[0] = f2b(f0.x); a[1] = f2b(f0.y); a[2] = f2b(f0.z); a[3] = f2b(f0.w);
            a[4] = f2b(f1.x); a[5] = f2b(f1.y); a[6] = f2b(f1.z); a[7] = f2b(f1.w);
            afr[mi] = a;
        }
#pragma unroll
        for (int nj = 0; nj < 4; ++nj)
            bfr[nj] = *reinterpret_cast<const s16x8*>(brow[nj] + k0);
#pragma unroll
        for (int mi = 0; mi < 4; ++mi)
#pragma unroll
            for (int nj = 0; nj < 4; ++nj)
                acc[mi][nj] = __builtin_amdgcn_mfma_f32_16x16x32_bf16(
                    afr[mi], bfr[nj], acc[mi][nj], 0, 0, 0);
    }

#pragma unroll
    for (int nj = 0; nj < 4; ++nj) {
        int col = w * 64 + nj * 16 + lr;
        float bias = b1[col];
#pragma unroll
        for (int mi = 0; mi < 4; ++mi)
#pragma unroll
            for (int q = 0; q < 4; ++q) {
                int row = mi * 16 + lh * 4 + q;
                hid_s[row * HID_STRIDE + col] = f2b(fmaxf(acc[mi][nj][q] + bias, 0.f));
            }
    }
    __syncthreads();

    f32x4 acc2[4];
#pragma unroll
    for (int i = 0; i < 4; ++i) acc2[i] = (f32x4)0.f;
    const int cw = w * 16;
    const unsigned short* b2row = W2T + (size_t)(cw + lr) * NHID;
    for (int ks = 0; ks < NHID; ks += 32) {
        int k0 = ks + lh * 8;
        s16x8 bfr = *reinterpret_cast<const s16x8*>(b2row + k0);
#pragma unroll
        for (int mi = 0; mi < 4; ++mi) {
            s16x8 afr = *reinterpret_cast<const s16x8*>(
                &hid_s[(mi * 16 + lr) * HID_STRIDE + k0]);
            acc2[mi] = __builtin_amdgcn_mfma_f32_16x16x32_bf16(afr, bfr, acc2[mi], 0, 0, 0);
        }
    }
    int col = cw + lr;
    float bias2 = b2[col];
#pragma unroll
    for (int mi = 0; mi < 4; ++mi)
#pragma unroll
        for (int q = 0; q < 4; ++q) {
            int row = m0 + mi * 16 + lh * 4 + q;
            if (row < N) h[(size_t)row * NCLS + col] = f2b(acc2[mi][q] + bias2);
        }
}

// ------- fused MFMA MLP (bf16-feat fast path, 1-deep software pipeline) -------
__global__ __launch_bounds__(256) void mlp_mfma_bf16_kernel(
    const unsigned short* __restrict__ feat, const unsigned short* __restrict__ W1T,
    const float* __restrict__ b1, const unsigned short* __restrict__ W2T,
    const float* __restrict__ b2, unsigned short* __restrict__ h, int N)
{
    __shared__ unsigned short hid_s[64 * HID_STRIDE];
    const int tid  = threadIdx.x;
    const int w    = tid >> 6;
    const int lane = tid & 63;
    const int lr   = lane & 15;
    const int lh   = lane >> 4;
    const int m0   = blockIdx.x * 64;
    const int koff = lh * 8;

    f32x4 acc[4][4];
#pragma unroll
    for (int i = 0; i < 4; ++i)
#pragma unroll
        for (int j = 0; j < 4; ++j) acc[i][j] = (f32x4)0.f;

    const unsigned short* arow[4];
#pragma unroll
    for (int mi = 0; mi < 4; ++mi) {
        int r = m0 + mi * 16 + lr;
        if (r > N - 1) r = N - 1;
        arow[mi] = feat + (size_t)r * NFEAT;
    }
    const unsigned short* brow[4];
#pragma unroll
    for (int nj = 0; nj < 4; ++nj)
        brow[nj] = W1T + (size_t)(w * 64 + nj * 16 + lr) * NFEAT;

    // software pipeline: named double buffers, issue step k+1 before MFMA of step k
    s16x8 pa0[4], pa1[4], pb0[4], pb1[4];
#pragma unroll
    for (int mi = 0; mi < 4; ++mi)
        pa0[mi] = *reinterpret_cast<const s16x8*>(arow[mi] + koff);
#pragma unroll
    for (int nj = 0; nj < 4; ++nj)
        pb0[nj] = *reinterpret_cast<const s16x8*>(brow[nj] + koff);

#pragma unroll
    for (int kb = 0; kb < NFEAT; kb += 64) {
        const int k1 = kb + 32 + koff;   // kb+32 <= 480 < NFEAT always
#pragma unroll
        for (int mi = 0; mi < 4; ++mi)
            pa1[mi] = *reinterpret_cast<const s16x8*>(arow[mi] + k1);
#pragma unroll
        for (int nj = 0; nj < 4; ++nj)
            pb1[nj] = *reinterpret_cast<const s16x8*>(brow[nj] + k1);
#pragma unroll
        for (int mi = 0; mi < 4; ++mi)
#pragma unroll
            for (int nj = 0; nj < 4; ++nj)
                acc[mi][nj] = __builtin_amdgcn_mfma_f32_16x16x32_bf16(
                    pa0[mi], pb0[nj], acc[mi][nj], 0, 0, 0);
        if (kb + 64 < NFEAT) {
            const int k2 = kb + 64 + koff;
#pragma unroll
            for (int mi = 0; mi < 4; ++mi)
                pa0[mi] = *reinterpret_cast<const s16x8*>(arow[mi] + k2);
#pragma unroll
            for (int nj = 0; nj < 4; ++nj)
                pb0[nj] = *reinterpret_cast<const s16x8*>(brow[nj] + k2);
        }
#pragma unroll
        for (int mi = 0; mi < 4; ++mi)
#pragma unroll
            for (int nj = 0; nj < 4; ++nj)
                acc[mi][nj] = __builtin_amdgcn_mfma_f32_16x16x32_bf16(
                    pa1[mi], pb1[nj], acc[mi][nj], 0, 0, 0);
    }

#pragma unroll
    for (int nj = 0; nj < 4; ++nj) {
        int col = w * 64 + nj * 16 + lr;
        float bias = b1[col];
#pragma unroll
        for (int mi = 0; mi < 4; ++mi)
#pragma unroll
            for (int q = 0; q < 4; ++q) {
                int row = mi * 16 + lh * 4 + q;
                hid_s[row * HID_STRIDE + col] = f2b(fmaxf(acc[mi][nj][q] + bias, 0.f));
            }
    }
    __syncthreads();

    f32x4 acc2[4];
#pragma unroll
    for (int i = 0; i < 4; ++i) acc2[i] = (f32x4)0.f;
    const int cw = w * 16;
    const unsigned short* b2row = W2T + (size_t)(cw + lr) * NHID;
    for (int ks = 0; ks < NHID; ks += 32) {
        int k0 = ks + lh * 8;
        s16x8 bfr = *reinterpret_cast<const s16x8*>(b2row + k0);
#pragma unroll
        for (int mi = 0; mi < 4; ++mi) {
            s16x8 afr = *reinterpret_cast<const s16x8*>(
                &hid_s[(mi * 16 + lr) * HID_STRIDE + k0]);
            acc2[mi] = __builtin_amdgcn_mfma_f32_16x16x32_bf16(afr, bfr, acc2[mi], 0, 0, 0);
        }
    }
    int col = cw + lr;
    float bias2 = b2[col];
#pragma unroll
    for (int mi = 0; mi < 4; ++mi)
#pragma unroll
        for (int q = 0; q < 4; ++q) {
            int row = m0 + mi * 16 + lh * 4 + q;
            if (row < N) h[(size_t)row * NCLS + col] = f2b(acc2[mi][q] + bias2);
        }
}

// ---------------- 3-phase scan ----------------
__global__ __launch_bounds__(1024) void scanA_kernel(
    const int* __restrict__ cnt, int* __restrict__ excl, int* __restrict__ partials, int n)
{
    __shared__ int wsum[16];
    const int t = threadIdx.x, wid = t >> 6, lane = t & 63;
    const int i = blockIdx.x * 1024 + t;
    int c = (i < n) ? cnt[i] : 0;
    int x = c;
#pragma unroll
    for (int off = 1; off < 64; off <<= 1) {
        int y = __shfl_up(x, off);
        if (lane >= off) x += y;
    }
    if (lane == 63) wsum[wid] = x;
    __syncthreads();
    if (wid == 0 && lane < 16) {
        int wv = wsum[lane];
#pragma unroll
        for (int off = 1; off < 16; off <<= 1) {
            int y = __shfl_up(wv, off);
            if (lane >= off) wv += y;
        }
        wsum[lane] = wv;
    }
    __syncthreads();
    int woff = wid ? wsum[wid - 1] : 0;
    int incl = x + woff;
    if (i < n) excl[i] = incl - c;
    if (t == 1023) partials[blockIdx.x] = incl;
}

__global__ __launch_bounds__(256) void scanB_kernel(
    int* __restrict__ partials, int* __restrict__ total_out, int nb, int n)
{
    __shared__ int s[256];
    const int t = threadIdx.x;
    int v = (t < nb) ? partials[t] : 0;
    s[t] = v;
    __syncthreads();
    for (int off = 1; off < 256; off <<= 1) {
        int y = (t >= off) ? s[t - off] : 0;
        __syncthreads();
        s[t] += y;
        __syncthreads();
    }
    partials[t] = s[t] - v;
    if (t == 255) total_out[n] = s[255];
}

__global__ __launch_bounds__(1024) void scanC_kernel(
    int* __restrict__ arr, const int* __restrict__ partials, int n)
{
    const int i = blockIdx.x * 1024 + threadIdx.x;
    if (i < n) arr[i] += partials[blockIdx.x];
}

// ------------- 2-level scatter (round-8 proven) -------------
__global__ __launch_bounds__(256) void countP1_kernel(
    const int* __restrict__ erow, int* __restrict__ cnts, int E, int CE)
{
    __shared__ int c[NBUCKET];
    const int blk = blockIdx.x, t = threadIdx.x;
    for (int i = t; i < NBUCKET; i += 256) c[i] = 0;
    __syncthreads();
    const int e0 = blk * CE, e1 = min(e0 + CE, E);
    for (int e = e0 + t; e < e1; e += 256)
        atomicAdd(&c[erow[e] / RB2], 1);
    __syncthreads();
    for (int b = t; b < NBUCKET; b += 256)
        cnts[(size_t)b * NPB + blk] = c[b];
}

__global__ __launch_bounds__(256) void scatterA_kernel(
    const float* __restrict__ vals, const int* __restrict__ erow,
    const int* __restrict__ ecol, const int* __restrict__ S,
    unsigned long long* __restrict__ stage, int E, int CE)
{
    __shared__ int lcur[NBUCKET];
    const int blk = blockIdx.x, t = threadIdx.x;
    for (int b = t; b < NBUCKET; b += 256) lcur[b] = S[(size_t)b * NPB + blk];
    __syncthreads();
    const int e0 = blk * CE, e1 = min(e0 + CE, E);
    for (int e = e0 + t; e < e1; e += 256) {
        int r = erow[e];
        unsigned q = (unsigned)__float2int_rn(vals[e] * 1048576.f);
        if (q > 32767u) q = 32767u;
        unsigned lo = ((unsigned)ecol[e] << 15) | q;
        int pos = atomicAdd(&lcur[r / RB2], 1);
        stage[pos] = ((unsigned long long)(unsigned)r << 32) | lo;
    }
}

__global__ __launch_bounds__(256) void scatterB_kernel(
    const unsigned long long* __restrict__ stage, const int* __restrict__ S,
    unsigned* __restrict__ ep, int* __restrict__ row_ptr, int n, int E)
{
    __shared__ int hcnt[256];
    __shared__ int lcur[256];
    const int b = blockIdx.x, t = threadIdx.x;
    if (b == 0 && t == 0) row_ptr[n] = E;
    const int r0 = b * RB2;
    if (r0 >= n) return;
    const int nr = min(RB2, n - r0);
    const int s0 = S[(size_t)b * NPB];
    const int s1 = S[(size_t)(b + 1) * NPB];
    hcnt[t] = 0;
    __syncthreads();
    for (int i = s0 + t; i < s1; i += 256)
        atomicAdd(&hcnt[(int)(stage[i] >> 32) - r0], 1);
    __syncthreads();
    int v = hcnt[t];
    lcur[t] = v;
    __syncthreads();
    for (int off = 1; off < 256; off <<= 1) {
        int y = (t >= off) ? lcur[t - off] : 0;
        __syncthreads();
        lcur[t] += y;
        __syncthreads();
    }
    int excl = lcur[t] - v;
    if (t < nr) row_ptr[r0 + t] = s0 + excl;
    __syncthreads();
    lcur[t] = s0 + excl;
    __syncthreads();
    for (int i = s0 + t; i < s1; i += 256) {
        unsigned long long rec = stage[i];
        int r = (int)(rec >> 32);
        int p = atomicAdd(&lcur[r - r0], 1);
        ep[p] = (unsigned)rec;
    }
}

// ------- SPMM + APPNP update (bf16 state): x_out = 0.9*A*x_in + 0.1*h -------
// wave = 4 edge-groups x 16 lanes; 32-edge superstep. LAST=1 fuses log_softmax.
template<int LAST>
__global__ __launch_bounds__(256) void spmm_kernel(
    const unsigned short* __restrict__ x_in, const unsigned short* __restrict__ h,
    unsigned short* __restrict__ x_out, float* __restrict__ out,
    const int* __restrict__ row_ptr, const unsigned* __restrict__ ep, int n)
{
    const int wid = threadIdx.x >> 6, lane = threadIdx.x & 63;
    const int r = blockIdx.x * 4 + wid;
    if (r >= n) return;
    const int g  = lane >> 4;
    const int li = lane & 15;
    const int s = row_ptr[r], e_end = row_ptr[r + 1];

    float aA0 = 0.f, aA1 = 0.f, aA2 = 0.f, aA3 = 0.f;
    float aB0 = 0.f, aB1 = 0.f, aB2 = 0.f, aB3 = 0.f;
    float aC0 = 0.f, aC1 = 0.f, aC2 = 0.f, aC3 = 0.f;
    float aD0 = 0.f, aD1 = 0.f, aD2 = 0.f, aD3 = 0.f;
    int e0 = s;
    for (; e0 + 32 <= e_end; e0 += 32) {
        unsigned p1 = __builtin_nontemporal_load(ep + e0 + g);
        unsigned p2 = __builtin_nontemporal_load(ep + e0 + 4 + g);
        unsigned p3 = __builtin_nontemporal_load(ep + e0 + 8 + g);
        unsigned p4 = __builtin_nontemporal_load(ep + e0 + 12 + g);
        unsigned p5 = __builtin_nontemporal_load(ep + e0 + 16 + g);
        unsigned p6 = __builtin_nontemporal_load(ep + e0 + 20 + g);
        unsigned p7 = __builtin_nontemporal_load(ep + e0 + 24 + g);
        unsigned p8 = __builtin_nontemporal_load(ep + e0 + 28 + g);
        uint2 u1 = *reinterpret_cast<const uint2*>(x_in + ((size_t)(p1 >> 15) << 6) + (li << 2));
        uint2 u2 = *reinterpret_cast<const uint2*>(x_in + ((size_t)(p2 >> 15) << 6) + (li << 2));
        uint2 u3 = *reinterpret_cast<const uint2*>(x_in + ((size_t)(p3 >> 15) << 6) + (li << 2));
        uint2 u4 = *reinterpret_cast<const uint2*>(x_in + ((size_t)(p4 >> 15) << 6) + (li << 2));
        uint2 u5 = *reinterpret_cast<const uint2*>(x_in + ((size_t)(p5 >> 15) << 6) + (li << 2));
        uint2 u6 = *reinterpret_cast<const uint2*>(x_in + ((size_t)(p6 >> 15) << 6) + (li << 2));
        uint2 u7 = *reinterpret_cast<const uint2*>(x_in + ((size_t)(p7 >> 15) << 6) + (li << 2));
        uint2 u8 = *reinterpret_cast<const uint2*>(x_in + ((size_t)(p8 >> 15) << 6) + (li << 2));
        float v1 = (float)(p1 & 0x7fffu) * (1.f / 1048576.f);
        float v2 = (float)(p2 & 0x7fffu) * (1.f / 1048576.f);
        float v3 = (float)(p3 & 0x7fffu) * (1.f / 1048576.f);
        float v4 = (float)(p4 & 0x7fffu) * (1.f / 1048576.f);
        float v5 = (float)(p5 & 0x7fffu) * (1.f / 1048576.f);
        float v6 = (float)(p6 & 0x7fffu) * (1.f / 1048576.f);
        float v7 = (float)(p7 & 0x7fffu) * (1.f / 1048576.f);
        float v8 = (float)(p8 & 0x7fffu) * (1.f / 1048576.f);
        aA0 += v1 * blo(u1.x); aA1 += v1 * bhi(u1.x);
        aA2 += v1 * blo(u1.y); aA3 += v1 * bhi(u1.y);
        aB0 += v2 * blo(u2.x); aB1 += v2 * bhi(u2.x);
        aB2 += v2 * blo(u2.y); aB3 += v2 * bhi(u2.y);
        aC0 += v3 * blo(u3.x); aC1 += v3 * bhi(u3.x);
        aC2 += v3 * blo(u3.y); aC3 += v3 * bhi(u3.y);
        aD0 += v4 * blo(u4.x); aD1 += v4 * bhi(u4.x);
        aD2 += v4 * blo(u4.y); aD3 += v4 * bhi(u4.y);
        aA0 += v5 * blo(u5.x); aA1 += v5 * bhi(u5.x);
        aA2 += v5 * blo(u5.y); aA3 += v5 * bhi(u5.y);
        aB0 += v6 * blo(u6.x); aB1 += v6 * bhi(u6.x);
        aB2 += v6 * blo(u6.y); aB3 += v6 * bhi(u6.y);
        aC0 += v7 * blo(u7.x); aC1 += v7 * bhi(u7.x);
        aC2 += v7 * blo(u7.y); aC3 += v7 * bhi(u7.y);
        aD0 += v8 * blo(u8.x); aD1 += v8 * bhi(u8.x);
        aD2 += v8 * blo(u8.y); aD3 += v8 * bhi(u8.y);
    }
    for (; e0 + 16 <= e_end; e0 += 16) {
        unsigned p1 = __builtin_nontemporal_load(ep + e0 + g);
        unsigned p2 = __builtin_nontemporal_load(ep + e0 + 4 + g);
        unsigned p3 = __builtin_nontemporal_load(ep + e0 + 8 + g);
        unsigned p4 = __builtin_nontemporal_load(ep + e0 + 12 + g);
        uint2 u1 = *reinterpret_cast<const uint2*>(x_in + ((size_t)(p1 >> 15) << 6) + (li << 2));
        uint2 u2 = *reinterpret_cast<const uint2*>(x_in + ((size_t)(p2 >> 15) << 6) + (li << 2));
        uint2 u3 = *reinterpret_cast<const uint2*>(x_in + ((size_t)(p3 >> 15) << 6) + (li << 2));
        uint2 u4 = *reinterpret_cast<const uint2*>(x_in + ((size_t)(p4 >> 15) << 6) + (li << 2));
        float v1 = (float)(p1 & 0x7fffu) * (1.f / 1048576.f);
        float v2 = (float)(p2 & 0x7fffu) * (1.f / 1048576.f);
        float v3 = (float)(p3 & 0x7fffu) * (1.f / 1048576.f);
        float v4 = (float)(p4 & 0x7fffu) * (1.f / 1048576.f);
        aA0 += v1 * blo(u1.x); aA1 += v1 * bhi(u1.x);
        aA2 += v1 * blo(u1.y); aA3 += v1 * bhi(u1.y);
        aB0 += v2 * blo(u2.x); aB1 += v2 * bhi(u2.x);
        aB2 += v2 * blo(u2.y); aB3 += v2 * bhi(u2.y);
        aC0 += v3 * blo(u3.x); aC1 += v3 * bhi(u3.x);
        aC2 += v3 * blo(u3.y); aC3 += v3 * bhi(u3.y);
        aD0 += v4 * blo(u4.x); aD1 += v4 * bhi(u4.x);
        aD2 += v4 * blo(u4.y); aD3 += v4 * bhi(u4.y);
    }
    for (; e0 < e_end; e0 += 4) {
        int e = e0 + g;
        if (e < e_end) {
            unsigned p = __builtin_nontemporal_load(ep + e);
            int   c = (int)(p >> 15);
            float v = (float)(p & 0x7fffu) * (1.f / 1048576.f);
            uint2 u = *reinterpret_cast<const uint2*>(x_in + ((size_t)c << 6) + (li << 2));
            aA0 += v * blo(u.x); aA1 += v * bhi(u.x);
            aA2 += v * blo(u.y); aA3 += v * bhi(u.y);
        }
    }
    float a0 = (aA0 + aB0) + (aC0 + aD0);
    float a1 = (aA1 + aB1) + (aC1 + aD1);
    float a2 = (aA2 + aB2) + (aC2 + aD2);
    float a3 = (aA3 + aB3) + (aC3 + aD3);
#pragma unroll
    for (int off = 16; off < 64; off <<= 1) {
        a0 += __shfl_xor(a0, off);
        a1 += __shfl_xor(a1, off);
        a2 += __shfl_xor(a2, off);
        a3 += __shfl_xor(a3, off);
    }
    if (g == 0) {
        size_t o = ((size_t)r << 6) + (li << 2);
        const unsigned* hp = reinterpret_cast<const unsigned*>(h + o);
        unsigned hx = __builtin_nontemporal_load(hp);
        unsigned hy = __builtin_nontemporal_load(hp + 1);
        float r0 = (1.f - ALPHA_C) * a0 + ALPHA_C * blo(hx);
        float r1 = (1.f - ALPHA_C) * a1 + ALPHA_C * bhi(hx);
        float r2 = (1.f - ALPHA_C) * a2 + ALPHA_C * blo(hy);
        float r3 = (1.f - ALPHA_C) * a3 + ALPHA_C * bhi(hy);
        if (LAST) {
            float m = fmaxf(fmaxf(r0, r1), fmaxf(r2, r3));
#pragma unroll
            for (int off = 1; off < 16; off <<= 1) m = fmaxf(m, __shfl_xor(m, off));
            float sum = expf(r0 - m) + expf(r1 - m) + expf(r2 - m) + expf(r3 - m);
#pragma unroll
            for (int off = 1; off < 16; off <<= 1) sum += __shfl_xor(sum, off);
            float ls = logf(sum);
            float4 ov;
            ov.x = (r0 - m) - ls;
            ov.y = (r1 - m) - ls;
            ov.z = (r2 - m) - ls;
            ov.w = (r3 - m) - ls;
            *reinterpret_cast<float4*>(out + o) = ov;
        } else {
            unsigned* op = reinterpret_cast<unsigned*>(x_out + o);
            __builtin_nontemporal_store(((unsigned)f2b(r1) << 16) | f2b(r0), op);
            __builtin_nontemporal_store(((unsigned)f2b(r3) << 16) | f2b(r2), op + 1);
        }
    }
}

extern "C" void kernel_launch(void* const* d_in, const int* in_sizes, int n_in,
                              void* d_out, int out_size, void* d_ws, size_t ws_size,
                              hipStream_t stream)
{
    const float* feat = (const float*)d_in[0];
    const float* W1   = (const float*)d_in[1];
    const float* b1   = (const float*)d_in[2];
    const float* W2   = (const float*)d_in[3];
    const float* b2   = (const float*)d_in[4];
    const float* vals = (const float*)d_in[5];
    const int*   erow = (const int*)d_in[6];
    const int*   ecol = (const int*)d_in[7];
    const int N = in_sizes[0] / NFEAT;
    const int E = in_sizes[5];
    float* out = (float*)d_out;
    const int CE = (E + NPB - 1) / NPB;
    const int NC = NBUCKET * NPB;

    size_t off = 0;
    auto alloc = [&](size_t bytes) -> void* {
        void* p = (char*)d_ws + off;
        off += (bytes + 255) & ~(size_t)255;
        return p;
    };
    unsigned short*     h        = (unsigned short*)alloc((size_t)N * NCLS * 2);
    unsigned short*     xA       = (unsigned short*)alloc((size_t)N * NCLS * 2);
    unsigned short*     xB       = (unsigned short*)alloc((size_t)N * NCLS * 2);
    int*                row_ptr  = (int*)alloc((size_t)(N + 1) * 4);
    int*                cnts     = (int*)alloc((size_t)NC * 4);
    int*                S        = (int*)alloc((size_t)(NC + 1) * 4);
    int*                partials = (int*)alloc(256 * 4);
    unsigned*           ep       = (unsigned*)alloc((size_t)E * 4);
    unsigned long long* stage    = (unsigned long long*)alloc((size_t)E * 8);
    unsigned short*     W1T      = (unsigned short*)alloc((size_t)NHID * NFEAT * 2);
    unsigned short*     W2T      = (unsigned short*)alloc((size_t)NCLS * NHID * 2);
    // optional fast-path buffer (102.4 MB) -- only used if ws is big enough
    size_t off_before_featb = off;
    unsigned short*     featb    = (unsigned short*)alloc((size_t)N * NFEAT * 2);
    const bool use_bf16_feat = (off <= ws_size);
    if (!use_bf16_feat) off = off_before_featb;

    // 0. weight transpose+convert (tiny)
    cvtT_kernel<<<(NFEAT * NHID + 255) / 256, 256, 0, stream>>>(W1, W1T, NFEAT, 8);
    cvtT_kernel<<<(NHID * NCLS + 255) / 256, 256, 0, stream>>>(W2, W2T, NHID, 6);

    // 1. MLP: bf16-feat fast path when ws permits (two-pass + pipelined K-loop)
    if (use_bf16_feat) {
        const long n8 = (long)N * NFEAT / 8;
        cvtF_kernel<<<(int)((n8 + 255) / 256), 256, 0, stream>>>(feat, featb, n8);
        mlp_mfma_bf16_kernel<<<(N + 63) / 64, 256, 0, stream>>>(featb, W1T, b1, W2T, b2, h, N);
    } else {
        mlp_mfma_kernel<<<(N + 63) / 64, 256, 0, stream>>>(feat, W1T, b1, W2T, b2, h, N);
    }

    // 2. 2-level scatter -> CSR (round-8 proven)
    countP1_kernel<<<NPB, 256, 0, stream>>>(erow, cnts, E, CE);
    scanA_kernel<<<NC / 1024, 1024, 0, stream>>>(cnts, S, partials, NC);
    scanB_kernel<<<1, 256, 0, stream>>>(partials, S, 256, NC);
    scanC_kernel<<<NC / 1024, 1024, 0, stream>>>(S, partials, NC);
    scatterA_kernel<<<NPB, 256, 0, stream>>>(vals, erow, ecol, S, stage, E, CE);
    scatterB_kernel<<<NBUCKET, 256, 0, stream>>>(stage, S, ep, row_ptr, N, E);

    // 3. K=10 propagation; iteration 10 fuses log_softmax and writes d_out
    const int gprop = (N + 3) / 4;
    const unsigned short* cur = h;
    for (int i = 0; i < 9; ++i) {
        unsigned short* dst = (i & 1) ? xB : xA;
        spmm_kernel<0><<<gprop, 256, 0, stream>>>(cur, h, dst, nullptr, row_ptr, ep, N);
        cur = dst;
    }
    spmm_kernel<1><<<gprop, 256, 0, stream>>>(cur, h, nullptr, out, row_ptr, ep, N);
}